// Round 2
// baseline (740.088 us; speedup 1.0000x reference)
//
#include <hip/hip_runtime.h>

// QRNN: y = inp @ W^T + b -> z=tanh(y0), f=sig(y1), o=sig(y2)
//       h_t = f*z + (1-f)*h;  out0 = sig(o)*h [B,S,H];  out1 = h_{S-1} [B,H]
// Established: inputs fp32, output fp32; gates stored ACTIVATED (r5).
// r6: GEMM moved to m97 structure (bf16 pre-convert + global_load_lds w=16,
//     pre-swizzled global source, linear LDS dest). 1003 -> 335 us.
// r7 (this round):
//   - K2/K3 scans were ~340 us (>2x BW-ideal): scalar 4B gate loads
//     (G13: hipcc won't widen). Vectorize to float4/thread, C 16->64 (L=32)
//     so grid stays 1024 blocks after 4x per-thread widening.
//   - GEMM: T1 XCD-aware bijective blockIdx swizzle (m204). FETCH was 289MB
//     vs ~75MB ideal (A-panel sharers scattered over 8 L2s).

typedef unsigned short ushort_t;
typedef __bf16 bf16x8 __attribute__((ext_vector_type(8)));
typedef float f32x4 __attribute__((ext_vector_type(4)));
typedef ushort_t us8 __attribute__((ext_vector_type(8)));

__device__ __forceinline__ ushort_t f2bf(float f) {
  unsigned int x = __builtin_bit_cast(unsigned int, f);
  x += 0x7fffu + ((x >> 16) & 1u);  // RNE
  return (ushort_t)(x >> 16);
}
__device__ __forceinline__ float bf2f(ushort_t u) {
  unsigned int x = ((unsigned int)u) << 16;
  return __builtin_bit_cast(float, x);
}
__device__ __forceinline__ void storeg(float* p, float v) { *p = v; }
__device__ __forceinline__ void storeg(ushort_t* p, float v) { *p = f2bf(v); }

// 4-wide gate loads (fp32 or bf16 fallback)
__device__ __forceinline__ f32x4 loadg4(const float* p) {
  return *(const f32x4*)p;
}
__device__ __forceinline__ f32x4 loadg4(const ushort_t* p) {
  ushort4 u = *(const ushort4*)p;
  f32x4 r;
  r[0] = bf2f(u.x); r[1] = bf2f(u.y); r[2] = bf2f(u.z); r[3] = bf2f(u.w);
  return r;
}
__device__ __forceinline__ f32x4 fma4(f32x4 a, f32x4 b, f32x4 c) {
  f32x4 r;
#pragma unroll
  for (int k = 0; k < 4; ++k) r[k] = fmaf(a[k], b[k], c[k]);
  return r;
}

__device__ __forceinline__ float sig_f(float x) { return 1.0f / (1.0f + __expf(-x)); }
__device__ __forceinline__ float tanh_f(float x) { return 1.0f - 2.0f / (1.0f + __expf(2.0f * x)); }

// async global->LDS, 16B per lane; LDS dest is WAVE-UNIFORM base + lane*16.
__device__ __forceinline__ void gload_lds16(const ushort_t* g, ushort_t* l) {
  __builtin_amdgcn_global_load_lds(
      (const __attribute__((address_space(1))) void*)g,
      (__attribute__((address_space(3))) void*)l, 16, 0, 0);
}

// ---------------- K0: fp32 -> bf16 pre-convert (RNE) ----------------
__global__ void __launch_bounds__(256) cvt_f32_bf16(
    const float* __restrict__ in, ushort_t* __restrict__ out, long n8) {
  long i = (long)blockIdx.x * 256 + threadIdx.x;
  const long stride = (long)gridDim.x * 256;
  for (; i < n8; i += stride) {
    const float4 a = ((const float4*)in)[2 * i];
    const float4 c = ((const float4*)in)[2 * i + 1];
    us8 w;
    w[0] = f2bf(a.x); w[1] = f2bf(a.y); w[2] = f2bf(a.z); w[3] = f2bf(a.w);
    w[4] = f2bf(c.x); w[5] = f2bf(c.y); w[6] = f2bf(c.z); w[7] = f2bf(c.w);
    ((us8*)out)[i] = w;
  }
}

// ---------------- K1: GEMM + activation epilogue ----------------
// A [M,K] bf16, Wt [N,K] bf16 (B^T layout), out [M,N] ACTIVATED gates.
// 128x128 tile, BK=64, 4 waves 2x2, each wave 4x4 MFMA 16x16x32 tiles.
// LDS: linear [row][64] bf16 dest for global_load_lds; swizzle realized by
// fetching global k-group (slot ^ (row&7)) -> read path XOR unchanged.
template <typename GT>
__global__ void __launch_bounds__(256) gemm_gates(
    const ushort_t* __restrict__ A, const ushort_t* __restrict__ Wt,
    const float* __restrict__ bias, GT* __restrict__ out,
    int M, int N, int K) {
  constexpr int BK = 64;
  __shared__ __align__(16) ushort_t As[128 * BK];
  __shared__ __align__(16) ushort_t Bs[128 * BK];
  const int tid = threadIdx.x;
  const int lane = tid & 63;
  const int wv = tid >> 6;  // 0..3

  // T1: XCD-aware bijective swizzle (m204). Each XCD gets a contiguous
  // chunk of the grid -> A-panel sharers hit the same L2.
  const int nwg = gridDim.x;
  const int bid0 = blockIdx.x;
  const int q = nwg >> 3, r = nwg & 7;
  const int xcd = bid0 & 7, loc = bid0 >> 3;
  const int bid = (xcd < r ? xcd * (q + 1) : r * (q + 1) + (xcd - r) * q) + loc;

  const int nblk = N >> 7;
  const int bn = bid % nblk;
  const int bm = bid / nblk;
  const int m0 = bm << 7, n0 = bn << 7;
  const int wm = (wv >> 1) << 6, wn = (wv & 1) << 6;

  f32x4 acc[4][4] = {};

  // Staging geometry: per wave-issue, 64 lanes cover 8 rows x 8 slots of 16B.
  const int srow = lane >> 3;       // row within 8-row group
  const int sg = (lane & 7) ^ srow; // pre-swizzled global 16B k-group

  for (int kt = 0; kt < K; kt += BK) {
    __syncthreads();
#pragma unroll
    for (int i = 0; i < 4; ++i) {
      const int rbase = wv * 32 + i * 8;  // wave-uniform
      gload_lds16(&A[(size_t)(m0 + rbase + srow) * K + kt + sg * 8],
                  &As[rbase * 64]);
      gload_lds16(&Wt[(size_t)(n0 + rbase + srow) * K + kt + sg * 8],
                  &Bs[rbase * 64]);
    }
    __syncthreads();  // compiler emits vmcnt(0) drain here (m97 structure)
#pragma unroll
    for (int ks = 0; ks < 2; ++ks) {
      bf16x8 af[4], bfr[4];
#pragma unroll
      for (int t = 0; t < 4; ++t) {
        const int ar = wm + t * 16 + (lane & 15);
        const int ag = ((ks << 2) + (lane >> 4)) ^ (ar & 7);
        af[t] = *(const bf16x8*)&As[ar * 64 + ag * 8];
        const int br = wn + t * 16 + (lane & 15);
        const int bg = ((ks << 2) + (lane >> 4)) ^ (br & 7);
        bfr[t] = *(const bf16x8*)&Bs[br * 64 + bg * 8];
      }
#pragma unroll
      for (int i = 0; i < 4; ++i)
#pragma unroll
        for (int j = 0; j < 4; ++j)
          acc[i][j] =
              __builtin_amdgcn_mfma_f32_16x16x32_bf16(af[i], bfr[j], acc[i][j], 0, 0, 0);
    }
  }

  // Epilogue. C/D layout (m89/m91): col = lane&15, row = (lane>>4)*4 + reg.
  const int gcat = n0 >> 10;  // 0:z(tanh) 1:f(sig) 2:o(sig); uniform per block
  const int cn = lane & 15;
  const int cm = (lane >> 4) << 2;
#pragma unroll
  for (int j = 0; j < 4; ++j) {
    const int n = n0 + wn + j * 16 + cn;
    const float bv = bias[n];
#pragma unroll
    for (int i = 0; i < 4; ++i) {
#pragma unroll
      for (int r = 0; r < 4; ++r) {
        const int m = m0 + wm + i * 16 + cm + r;
        const float y = acc[i][j][r] + bv;
        const float v = (gcat == 0) ? tanh_f(y) : sig_f(y);
        storeg(&out[(size_t)m * N + n], v);
      }
    }
  }
}

// ---------------- K2: chunk aggregates (float4/thread) ----------------
// h_t = f*z + (1-f)*h == g*h + a, g=1-f, a=f*z. Chunk: h_end = Aa + G*h_in.
// grid: Bg * C * (H/1024); 256 threads, each owns 4 h-channels.
template <typename GT>
__global__ void __launch_bounds__(256) qrnn_chunk_agg(
    const GT* __restrict__ gates, float* __restrict__ aggG,
    float* __restrict__ aggA, int b0, int S, int H, int C, int L) {
  const int nhb = H >> 10;
  const int hb = blockIdx.x % nhb;
  const int c = (blockIdx.x / nhb) % C;
  const int bl = blockIdx.x / (nhb * C);  // local batch within group
  const int h = (hb << 10) + threadIdx.x * 4;
  const int N3 = 3 * H;
  const GT* pz = gates + ((size_t)(bl * S + c * L)) * N3 + h;
  const GT* pf = pz + H;
  f32x4 G = {1.0f, 1.0f, 1.0f, 1.0f};
  f32x4 Aa = {0.0f, 0.0f, 0.0f, 0.0f};
#pragma unroll 4
  for (int j = 0; j < L; ++j) {
    const f32x4 z = loadg4(pz);
    const f32x4 f = loadg4(pf);
    const f32x4 g = 1.0f - f;
    Aa = fma4(g, Aa, f * z);
    G *= g;
    pz += N3;
    pf += N3;
  }
  const size_t idx = ((size_t)((b0 + bl) * C + c)) * H + h;
  *(f32x4*)&aggG[idx] = G;
  *(f32x4*)&aggA[idx] = Aa;
}

// ---------------- K3: prefix fold + replay + output gate ----------------
// gates hold ACTIVATED z,f,o -> o is used DIRECTLY (no second sigmoid).
template <typename GT>
__global__ void __launch_bounds__(256) qrnn_scan_apply(
    const GT* __restrict__ gates, const float* __restrict__ aggG,
    const float* __restrict__ aggA, float* __restrict__ out,
    int b0, int B, int S, int H, int C, int L) {
  const int nhb = H >> 10;
  const int hb = blockIdx.x % nhb;
  const int c = (blockIdx.x / nhb) % C;
  const int bl = blockIdx.x / (nhb * C);
  const int bg = b0 + bl;  // global batch
  const int h = (hb << 10) + threadIdx.x * 4;
  const int N3 = 3 * H;

  f32x4 hc = {0.0f, 0.0f, 0.0f, 0.0f};  // h at chunk start (c uniform)
  for (int cc = 0; cc < c; ++cc) {
    const size_t idx = ((size_t)(bg * C + cc)) * H + h;
    hc = fma4(*(const f32x4*)&aggG[idx], hc, *(const f32x4*)&aggA[idx]);
  }

  const GT* pz = gates + ((size_t)(bl * S + c * L)) * N3 + h;
  const GT* pf = pz + H;
  const GT* po = pf + H;
  size_t oidx = ((size_t)(bg * S + c * L)) * H + h;
#pragma unroll 4
  for (int j = 0; j < L; ++j) {
    const f32x4 z = loadg4(pz);
    const f32x4 f = loadg4(pf);
    const f32x4 o = loadg4(po);  // already sigmoid(y_o)
    hc = fma4(1.0f - f, hc, f * z);
    *(f32x4*)&out[oidx] = o * hc;
    pz += N3; pf += N3; po += N3; oidx += H;
  }
  if (c == C - 1) {  // final state c[:, -1] -> second output [B,H]
    *(f32x4*)&out[(size_t)B * S * H + (size_t)bg * H + h] = hc;
  }
}

template <typename GT>
static void run_groups(const float* inp, const ushort_t* Wbf, const float* b,
                       float* out, ushort_t* Abf, void* gates_ws, float* aggG,
                       float* aggA, int Bg, int B, int S, int H, int K, int C,
                       int L, hipStream_t stream) {
  const int N = 3 * H;
  GT* gates = (GT*)gates_ws;
  for (int b0 = 0; b0 < B; b0 += Bg) {
    const int Mg = Bg * S;
    // K0: convert this group's inp slab to bf16
    const long n8 = (long)Mg * K / 8;
    const long cg = (n8 + 255) / 256;
    const int cgrid = (int)(cg < 2048 ? cg : 2048);
    cvt_f32_bf16<<<cgrid, 256, 0, stream>>>(inp + (size_t)b0 * S * K, Abf, n8);
    const int gemm_grid = (Mg / 128) * (N / 128);
    const int scan_grid = Bg * C * (H / 1024);
    gemm_gates<GT><<<gemm_grid, 256, 0, stream>>>(Abf, Wbf, b, gates, Mg, N, K);
    qrnn_chunk_agg<GT><<<scan_grid, 256, 0, stream>>>(
        gates, aggG, aggA, b0, S, H, C, L);
    qrnn_scan_apply<GT><<<scan_grid, 256, 0, stream>>>(
        gates, aggG, aggA, out, b0, B, S, H, C, L);
  }
}

extern "C" void kernel_launch(void* const* d_in, const int* in_sizes, int n_in,
                              void* d_out, int out_size, void* d_ws, size_t ws_size,
                              hipStream_t stream) {
  (void)in_sizes; (void)n_in; (void)out_size;
  const float* inp = (const float*)d_in[0];  // [B,S,D] fp32
  const float* W = (const float*)d_in[1];    // [3H,D] fp32
  const float* b = (const float*)d_in[2];    // [3H] fp32
  float* out = (float*)d_out;                // [B,S,H] ++ [B,H] fp32

  constexpr int B = 16, S = 2048, H = 1024, K = 1024;
  constexpr int C = 64, L = S / C;  // r7: C 16->64 (keeps scan grid at 1024
                                    // blocks after float4 widening)
  const int N3 = 3 * H;

  // ws layout: [aggG fp32 B*C*H][aggA fp32 B*C*H][Wbf bf16 3H*K]
  //            [Abf bf16 Bg*S*K][gates (group-local)]
  const size_t agg_elems = (size_t)B * C * H;
  float* aggG = (float*)d_ws;
  float* aggA = aggG + agg_elems;
  ushort_t* Wbf = (ushort_t*)(aggA + agg_elems);
  ushort_t* Abf = Wbf + (size_t)N3 * K;
  const size_t hdr =
      2 * agg_elems * sizeof(float) + (size_t)N3 * K * sizeof(ushort_t);

  // Largest batch-group whose (Abf + gates) fit; prefer fp32 gates (exact scan).
  int Bg = 0;
  bool f32g = true;
  for (int g = 16; g >= 1; g >>= 1) {
    const size_t need =
        hdr + (size_t)g * S * K * sizeof(ushort_t) + (size_t)g * S * N3 * sizeof(float);
    if (need <= ws_size) { Bg = g; break; }
  }
  if (!Bg) {
    f32g = false;
    for (int g = 16; g >= 1; g >>= 1) {
      const size_t need = hdr + (size_t)g * S * K * sizeof(ushort_t) +
                          (size_t)g * S * N3 * sizeof(ushort_t);
      if (need <= ws_size) { Bg = g; break; }
    }
  }
  if (!Bg) return;
  void* gates_ws = (void*)(Abf + (size_t)Bg * S * K);

  // Convert W once (RNE, identical numerics to the in-GEMM convert).
  {
    const long n8w = (long)N3 * K / 8;
    const long cg = (n8w + 255) / 256;
    const int grid = (int)(cg < 2048 ? cg : 2048);
    cvt_f32_bf16<<<grid, 256, 0, stream>>>(W, Wbf, n8w);
  }

  if (f32g) {
    run_groups<float>(inp, Wbf, b, out, Abf, gates_ws, aggG, aggA, Bg,
                      B, S, H, K, C, L, stream);
  } else {
    run_groups<ushort_t>(inp, Wbf, b, out, Abf, gates_ws, aggG, aggA, Bg,
                         B, S, H, K, C, L, stream);
  }
}

// Round 3
// 585.637 us; speedup vs baseline: 1.2637x; 1.2637x over previous
//
#include <hip/hip_runtime.h>

// QRNN: y = inp @ W^T + b -> z=tanh(y0), f=sig(y1), o=sig(y2)
//       h_t = f*z + (1-f)*h;  out0 = sig(o)*h [B,S,H];  out1 = h_{S-1} [B,H]
// Established: inputs fp32, output fp32; gates stored ACTIVATED (r5).
// r6: GEMM -> m97 structure (bf16 pre-convert + global_load_lds w=16,
//     pre-swizzled global source, linear LDS dest). 1003 -> 335 us.
// r7 post-mortem: (a) T1 XCD swizzle HURT here (FETCH 289->540 MB, +11 us):
//     W = 6.3 MB > 4 MB L2, consecutive-bid blocks thrash it; identity order
//     keeps only 3 W-panels per XCD resident. REVERTED. (b) float4 scans were
//     null: scans are traffic-bound, not issue-width-bound.
// r8 (this round): gates stored as fp16 (_Float16) instead of fp32.
//     -536 MB traffic (GEMM write 402->201, K2 read 268->134, K3 402->201);
//     gate array (201 MB) now fits L3. fp16 rel err 2^-11 on bounded gates
//     adds <=1e-3 to absmax (scan math stays fp32).

typedef unsigned short ushort_t;
typedef _Float16 half_t;
typedef __bf16 bf16x8 __attribute__((ext_vector_type(8)));
typedef float f32x4 __attribute__((ext_vector_type(4)));
typedef ushort_t us8 __attribute__((ext_vector_type(8)));
typedef half_t f16x4 __attribute__((ext_vector_type(4)));

__device__ __forceinline__ ushort_t f2bf(float f) {
  unsigned int x = __builtin_bit_cast(unsigned int, f);
  x += 0x7fffu + ((x >> 16) & 1u);  // RNE
  return (ushort_t)(x >> 16);
}
__device__ __forceinline__ float bf2f(ushort_t u) {
  unsigned int x = ((unsigned int)u) << 16;
  return __builtin_bit_cast(float, x);
}
__device__ __forceinline__ void storeg(float* p, float v) { *p = v; }
__device__ __forceinline__ void storeg(half_t* p, float v) { *p = (half_t)v; }

// 4-wide gate loads
__device__ __forceinline__ f32x4 loadg4(const float* p) {
  return *(const f32x4*)p;
}
__device__ __forceinline__ f32x4 loadg4(const half_t* p) {
  const f16x4 v = *(const f16x4*)p;  // 8B load
  f32x4 r;
  r[0] = (float)v[0]; r[1] = (float)v[1]; r[2] = (float)v[2]; r[3] = (float)v[3];
  return r;
}
__device__ __forceinline__ f32x4 fma4(f32x4 a, f32x4 b, f32x4 c) {
  f32x4 r;
#pragma unroll
  for (int k = 0; k < 4; ++k) r[k] = fmaf(a[k], b[k], c[k]);
  return r;
}

__device__ __forceinline__ float sig_f(float x) { return 1.0f / (1.0f + __expf(-x)); }
__device__ __forceinline__ float tanh_f(float x) { return 1.0f - 2.0f / (1.0f + __expf(2.0f * x)); }

// async global->LDS, 16B per lane; LDS dest is WAVE-UNIFORM base + lane*16.
__device__ __forceinline__ void gload_lds16(const ushort_t* g, ushort_t* l) {
  __builtin_amdgcn_global_load_lds(
      (const __attribute__((address_space(1))) void*)g,
      (__attribute__((address_space(3))) void*)l, 16, 0, 0);
}

// ---------------- K0: fp32 -> bf16 pre-convert (RNE) ----------------
__global__ void __launch_bounds__(256) cvt_f32_bf16(
    const float* __restrict__ in, ushort_t* __restrict__ out, long n8) {
  long i = (long)blockIdx.x * 256 + threadIdx.x;
  const long stride = (long)gridDim.x * 256;
  for (; i < n8; i += stride) {
    const float4 a = ((const float4*)in)[2 * i];
    const float4 c = ((const float4*)in)[2 * i + 1];
    us8 w;
    w[0] = f2bf(a.x); w[1] = f2bf(a.y); w[2] = f2bf(a.z); w[3] = f2bf(a.w);
    w[4] = f2bf(c.x); w[5] = f2bf(c.y); w[6] = f2bf(c.z); w[7] = f2bf(c.w);
    ((us8*)out)[i] = w;
  }
}

// ---------------- K1: GEMM + activation epilogue ----------------
// A [M,K] bf16, Wt [N,K] bf16 (B^T layout), out [M,N] ACTIVATED gates (fp16).
// 128x128 tile, BK=64, 4 waves 2x2, each wave 4x4 MFMA 16x16x32 tiles.
// LDS: linear [row][64] bf16 dest for global_load_lds; swizzle realized by
// fetching global k-group (slot ^ (row&7)) -> read path XOR unchanged.
// blockIdx mapping: IDENTITY (r7 showed XCD swizzle thrashes L2 on W here).
template <typename GT>
__global__ void __launch_bounds__(256) gemm_gates(
    const ushort_t* __restrict__ A, const ushort_t* __restrict__ Wt,
    const float* __restrict__ bias, GT* __restrict__ out,
    int M, int N, int K) {
  constexpr int BK = 64;
  __shared__ __align__(16) ushort_t As[128 * BK];
  __shared__ __align__(16) ushort_t Bs[128 * BK];
  const int tid = threadIdx.x;
  const int lane = tid & 63;
  const int wv = tid >> 6;  // 0..3

  const int bid = blockIdx.x;
  const int nblk = N >> 7;
  const int bn = bid % nblk;
  const int bm = bid / nblk;
  const int m0 = bm << 7, n0 = bn << 7;
  const int wm = (wv >> 1) << 6, wn = (wv & 1) << 6;

  f32x4 acc[4][4] = {};

  // Staging geometry: per wave-issue, 64 lanes cover 8 rows x 8 slots of 16B.
  const int srow = lane >> 3;       // row within 8-row group
  const int sg = (lane & 7) ^ srow; // pre-swizzled global 16B k-group

  for (int kt = 0; kt < K; kt += BK) {
    __syncthreads();
#pragma unroll
    for (int i = 0; i < 4; ++i) {
      const int rbase = wv * 32 + i * 8;  // wave-uniform
      gload_lds16(&A[(size_t)(m0 + rbase + srow) * K + kt + sg * 8],
                  &As[rbase * 64]);
      gload_lds16(&Wt[(size_t)(n0 + rbase + srow) * K + kt + sg * 8],
                  &Bs[rbase * 64]);
    }
    __syncthreads();  // compiler emits vmcnt(0) drain here (m97 structure)
#pragma unroll
    for (int ks = 0; ks < 2; ++ks) {
      bf16x8 af[4], bfr[4];
#pragma unroll
      for (int t = 0; t < 4; ++t) {
        const int ar = wm + t * 16 + (lane & 15);
        const int ag = ((ks << 2) + (lane >> 4)) ^ (ar & 7);
        af[t] = *(const bf16x8*)&As[ar * 64 + ag * 8];
        const int br = wn + t * 16 + (lane & 15);
        const int bg = ((ks << 2) + (lane >> 4)) ^ (br & 7);
        bfr[t] = *(const bf16x8*)&Bs[br * 64 + bg * 8];
      }
#pragma unroll
      for (int i = 0; i < 4; ++i)
#pragma unroll
        for (int j = 0; j < 4; ++j)
          acc[i][j] =
              __builtin_amdgcn_mfma_f32_16x16x32_bf16(af[i], bfr[j], acc[i][j], 0, 0, 0);
    }
  }

  // Epilogue. C/D layout (m89/m91): col = lane&15, row = (lane>>4)*4 + reg.
  const int gcat = n0 >> 10;  // 0:z(tanh) 1:f(sig) 2:o(sig); uniform per block
  const int cn = lane & 15;
  const int cm = (lane >> 4) << 2;
#pragma unroll
  for (int j = 0; j < 4; ++j) {
    const int n = n0 + wn + j * 16 + cn;
    const float bv = bias[n];
#pragma unroll
    for (int i = 0; i < 4; ++i) {
#pragma unroll
      for (int r = 0; r < 4; ++r) {
        const int m = m0 + wm + i * 16 + cm + r;
        const float y = acc[i][j][r] + bv;
        const float v = (gcat == 0) ? tanh_f(y) : sig_f(y);
        storeg(&out[(size_t)m * N + n], v);
      }
    }
  }
}

// ---------------- K2: chunk aggregates (4 channels/thread) ----------------
// h_t = f*z + (1-f)*h == g*h + a, g=1-f, a=f*z. Chunk: h_end = Aa + G*h_in.
// grid: Bg * C * (H/1024); 256 threads, each owns 4 h-channels.
template <typename GT>
__global__ void __launch_bounds__(256) qrnn_chunk_agg(
    const GT* __restrict__ gates, float* __restrict__ aggG,
    float* __restrict__ aggA, int b0, int S, int H, int C, int L) {
  const int nhb = H >> 10;
  const int hb = blockIdx.x % nhb;
  const int c = (blockIdx.x / nhb) % C;
  const int bl = blockIdx.x / (nhb * C);  // local batch within group
  const int h = (hb << 10) + threadIdx.x * 4;
  const int N3 = 3 * H;
  const GT* pz = gates + ((size_t)(bl * S + c * L)) * N3 + h;
  const GT* pf = pz + H;
  f32x4 G = {1.0f, 1.0f, 1.0f, 1.0f};
  f32x4 Aa = {0.0f, 0.0f, 0.0f, 0.0f};
#pragma unroll 4
  for (int j = 0; j < L; ++j) {
    const f32x4 z = loadg4(pz);
    const f32x4 f = loadg4(pf);
    const f32x4 g = 1.0f - f;
    Aa = fma4(g, Aa, f * z);
    G *= g;
    pz += N3;
    pf += N3;
  }
  const size_t idx = ((size_t)((b0 + bl) * C + c)) * H + h;
  *(f32x4*)&aggG[idx] = G;
  *(f32x4*)&aggA[idx] = Aa;
}

// ---------------- K3: prefix fold + replay + output gate ----------------
// gates hold ACTIVATED z,f,o -> o is used DIRECTLY (no second sigmoid).
template <typename GT>
__global__ void __launch_bounds__(256) qrnn_scan_apply(
    const GT* __restrict__ gates, const float* __restrict__ aggG,
    const float* __restrict__ aggA, float* __restrict__ out,
    int b0, int B, int S, int H, int C, int L) {
  const int nhb = H >> 10;
  const int hb = blockIdx.x % nhb;
  const int c = (blockIdx.x / nhb) % C;
  const int bl = blockIdx.x / (nhb * C);
  const int bg = b0 + bl;  // global batch
  const int h = (hb << 10) + threadIdx.x * 4;
  const int N3 = 3 * H;

  f32x4 hc = {0.0f, 0.0f, 0.0f, 0.0f};  // h at chunk start (c uniform)
  for (int cc = 0; cc < c; ++cc) {
    const size_t idx = ((size_t)(bg * C + cc)) * H + h;
    hc = fma4(*(const f32x4*)&aggG[idx], hc, *(const f32x4*)&aggA[idx]);
  }

  const GT* pz = gates + ((size_t)(bl * S + c * L)) * N3 + h;
  const GT* pf = pz + H;
  const GT* po = pf + H;
  size_t oidx = ((size_t)(bg * S + c * L)) * H + h;
#pragma unroll 4
  for (int j = 0; j < L; ++j) {
    const f32x4 z = loadg4(pz);
    const f32x4 f = loadg4(pf);
    const f32x4 o = loadg4(po);  // already sigmoid(y_o)
    hc = fma4(1.0f - f, hc, f * z);
    *(f32x4*)&out[oidx] = o * hc;
    pz += N3; pf += N3; po += N3; oidx += H;
  }
  if (c == C - 1) {  // final state c[:, -1] -> second output [B,H]
    *(f32x4*)&out[(size_t)B * S * H + (size_t)bg * H + h] = hc;
  }
}

template <typename GT>
static void run_groups(const float* inp, const ushort_t* Wbf, const float* b,
                       float* out, ushort_t* Abf, void* gates_ws, float* aggG,
                       float* aggA, int Bg, int B, int S, int H, int K, int C,
                       int L, hipStream_t stream) {
  const int N = 3 * H;
  GT* gates = (GT*)gates_ws;
  for (int b0 = 0; b0 < B; b0 += Bg) {
    const int Mg = Bg * S;
    // K0: convert this group's inp slab to bf16
    const long n8 = (long)Mg * K / 8;
    const long cg = (n8 + 255) / 256;
    const int cgrid = (int)(cg < 2048 ? cg : 2048);
    cvt_f32_bf16<<<cgrid, 256, 0, stream>>>(inp + (size_t)b0 * S * K, Abf, n8);
    const int gemm_grid = (Mg / 128) * (N / 128);
    const int scan_grid = Bg * C * (H / 1024);
    gemm_gates<GT><<<gemm_grid, 256, 0, stream>>>(Abf, Wbf, b, gates, Mg, N, K);
    qrnn_chunk_agg<GT><<<scan_grid, 256, 0, stream>>>(
        gates, aggG, aggA, b0, S, H, C, L);
    qrnn_scan_apply<GT><<<scan_grid, 256, 0, stream>>>(
        gates, aggG, aggA, out, b0, B, S, H, C, L);
  }
}

extern "C" void kernel_launch(void* const* d_in, const int* in_sizes, int n_in,
                              void* d_out, int out_size, void* d_ws, size_t ws_size,
                              hipStream_t stream) {
  (void)in_sizes; (void)n_in; (void)out_size;
  const float* inp = (const float*)d_in[0];  // [B,S,D] fp32
  const float* W = (const float*)d_in[1];    // [3H,D] fp32
  const float* b = (const float*)d_in[2];    // [3H] fp32
  float* out = (float*)d_out;                // [B,S,H] ++ [B,H] fp32

  constexpr int B = 16, S = 2048, H = 1024, K = 1024;
  constexpr int C = 64, L = S / C;
  const int N3 = 3 * H;

  // ws layout: [aggG fp32 B*C*H][aggA fp32 B*C*H][Wbf bf16 3H*K]
  //            [Abf bf16 Bg*S*K][gates fp16 (group-local)]
  const size_t agg_elems = (size_t)B * C * H;
  float* aggG = (float*)d_ws;
  float* aggA = aggG + agg_elems;
  ushort_t* Wbf = (ushort_t*)(aggA + agg_elems);
  ushort_t* Abf = Wbf + (size_t)N3 * K;
  const size_t hdr =
      2 * agg_elems * sizeof(float) + (size_t)N3 * K * sizeof(ushort_t);

  // Largest batch-group whose (Abf + fp16 gates) fit.
  int Bg = 0;
  for (int g = 16; g >= 1; g >>= 1) {
    const size_t need = hdr + (size_t)g * S * K * sizeof(ushort_t) +
                        (size_t)g * S * N3 * sizeof(half_t);
    if (need <= ws_size) { Bg = g; break; }
  }
  if (!Bg) return;
  void* gates_ws = (void*)(Abf + (size_t)Bg * S * K);

  // Convert W once (RNE, identical numerics to the in-GEMM convert).
  {
    const long n8w = (long)N3 * K / 8;
    const long cg = (n8w + 255) / 256;
    const int grid = (int)(cg < 2048 ? cg : 2048);
    cvt_f32_bf16<<<grid, 256, 0, stream>>>(W, Wbf, n8w);
  }

  run_groups<half_t>(inp, Wbf, b, out, Abf, gates_ws, aggG, aggA, Bg,
                     B, S, H, K, C, L, stream);
}